// Round 1
// baseline (1455.974 us; speedup 1.0000x reference)
//
#include <hip/hip_runtime.h>

// GCN layer: h = x @ W^T + b  [16384,128];  out = A_hat @ h  [16384,128]
// GEMM2 rebuilt as a BW-saturating streamer:
//   - A_hat staged via global_load_lds (1 KB contiguous per wave-instruction,
//     32 KB in flight per block) into double-buffered LDS
//   - T2 XOR swizzle (chunk ^= row&7) applied on the GLOBAL source + LDS read
//     (gload_lds dest must stay linear), conflict-free ds_read_b128
//   - grid 512 blocks (BM=32) -> 2 blocks/CU for barrier overlap
//   - hT (4 MB bf16, per-XCD-L2 resident) read direct per fragment

#define N_NODES 16384
#define IN_DIM  256
#define OUT_DIM 128

typedef short bf16x8 __attribute__((ext_vector_type(8)));
typedef float f32x4  __attribute__((ext_vector_type(4)));

typedef __attribute__((address_space(3))) unsigned int       lds_u32;
typedef __attribute__((address_space(1))) const unsigned int glb_u32;

// fp32 -> bf16 bits, round-to-nearest-even (inputs finite)
__device__ __forceinline__ unsigned short f2bf(float f) {
    unsigned u = __float_as_uint(f);
    u += 0x7fffu + ((u >> 16) & 1u);
    return (unsigned short)(u >> 16);
}

__device__ __forceinline__ bf16x8 load_cvt8(const float* __restrict__ p) {
    f32x4 a = *reinterpret_cast<const f32x4*>(p);
    f32x4 c = *reinterpret_cast<const f32x4*>(p + 4);
    bf16x8 r;
#pragma unroll
    for (int i = 0; i < 4; ++i) {
        r[i]     = (short)f2bf(a[i]);
        r[i + 4] = (short)f2bf(c[i]);
    }
    return r;
}

// async 16B global -> LDS (wave-uniform LDS base + lane*16 dest)
__device__ __forceinline__ void gload16(const float* src, float* dst) {
    __builtin_amdgcn_global_load_lds((glb_u32*)src, (lds_u32*)dst, 16, 0, 0);
}

// ---------------------------------------------------------------------------
// GEMM1: hT[o][n] = sum_k W[o][k] * x[n][k] + b[o]   (M=128 o, N=16384 n, K=256)
// Block 256 thr = 4 waves (2x2), tile 128(o) x 64(n); wave tile 64x32.
// Grid = 16384/64 = 256 blocks (fills all CUs).
// ---------------------------------------------------------------------------
__global__ __launch_bounds__(256) void gemm1_xw(
    const float* __restrict__ x, const float* __restrict__ W,
    const float* __restrict__ b, unsigned short* __restrict__ hT) {
    const int tid  = threadIdx.x;
    const int lane = tid & 63, wid = tid >> 6;
    const int l16  = lane & 15, quad = lane >> 4;
    const int n0   = blockIdx.x * 64;
    const int wm   = (wid >> 1) * 64;   // o-offset of wave
    const int wn   = (wid & 1) * 32;    // n-offset of wave

    f32x4 acc[4][2] = {};

    const float* aBase = W + (size_t)(wm + l16) * IN_DIM + quad * 8;
    const float* bBase = x + (size_t)(n0 + wn + l16) * IN_DIM + quad * 8;

#pragma unroll 2
    for (int k = 0; k < IN_DIM; k += 32) {
        bf16x8 af[4], bfr[2];
#pragma unroll
        for (int mf = 0; mf < 4; ++mf)
            af[mf] = load_cvt8(aBase + (size_t)mf * 16 * IN_DIM + k);
#pragma unroll
        for (int nf = 0; nf < 2; ++nf)
            bfr[nf] = load_cvt8(bBase + (size_t)nf * 16 * IN_DIM + k);
#pragma unroll
        for (int mf = 0; mf < 4; ++mf)
#pragma unroll
            for (int nf = 0; nf < 2; ++nf)
                acc[mf][nf] = __builtin_amdgcn_mfma_f32_16x16x32_bf16(
                    af[mf], bfr[nf], acc[mf][nf], 0, 0, 0);
    }

    // C/D layout: col = lane&15 (x-row n), row = quad*4 + reg (W-row o)
#pragma unroll
    for (int mf = 0; mf < 4; ++mf) {
#pragma unroll
        for (int i = 0; i < 4; ++i) {
            const int o    = wm + mf * 16 + quad * 4 + i;
            const float bo = b[o];
#pragma unroll
            for (int nf = 0; nf < 2; ++nf) {
                const int n = n0 + wn + nf * 16 + l16;
                hT[(size_t)o * N_NODES + n] = f2bf(acc[mf][nf][i] + bo);
            }
        }
    }
}

// ---------------------------------------------------------------------------
// GEMM2: out[m][o] = sum_j A_hat[m][j] * hT[o][j]   (M=16384, N=128, K=16384)
// Block 256 thr = 4 waves, tile BM=32(m) x 128(o); wave tile 32x32.
// Grid = 16384/32 = 512 blocks -> 2 blocks/CU.
// A staged: double-buffered LDS [2][32][256] f32 (64 KB), global_load_lds,
// one wave-instruction = one full 1 KB row chunk (DRAM-sequential).
// Swizzle: LDS chunk c of row r holds global chunk c ^ (r&7).
// ---------------------------------------------------------------------------
#define BM2 32
#define BK2 256
#define NT2 (N_NODES / BK2)   // 64 k-tiles

__global__ __launch_bounds__(256, 2) void gemm2_ah(
    const float* __restrict__ A, const unsigned short* __restrict__ hT,
    float* __restrict__ out) {
    __shared__ float sA[2][BM2][BK2];   // 64 KB

    const int tid  = threadIdx.x;
    const int lane = tid & 63, wid = tid >> 6;
    const int l16  = lane & 15, quad = lane >> 4;
    const int m0   = blockIdx.x * BM2;
    const int wn   = wid * 32;          // o-offset of wave

    f32x4 acc[2][2] = {};

    const unsigned short* bBase = hT + (size_t)(wn + l16) * N_NODES + quad * 8;

    // Stage k-tile kt into buffer bf. Round r: wave `wid` loads row r*4+wid,
    // lane = dest chunk (16B units); source chunk = lane ^ (row&7).
#define STAGE2(bf, kt) do {                                                   \
        _Pragma("unroll")                                                     \
        for (int r = 0; r < 8; ++r) {                                         \
            const int row_ = r * 4 + wid;                                     \
            const float* src_ = A + (size_t)(m0 + row_) * N_NODES             \
                              + (size_t)(kt) * BK2                            \
                              + ((lane ^ (row_ & 7)) << 2);                   \
            gload16(src_, &sA[bf][row_][0]);                                  \
        }                                                                     \
    } while (0)

    STAGE2(0, 0);
    asm volatile("s_waitcnt vmcnt(0)" ::: "memory");
    __syncthreads();

    int cur = 0;
    for (int kt = 0; kt < NT2; ++kt) {
        if (kt + 1 < NT2) STAGE2(cur ^ 1, kt + 1);

        const unsigned short* bk = bBase + (size_t)kt * BK2;
#pragma unroll
        for (int ks = 0; ks < 8; ++ks) {            // k = ks*32 within tile
            const int cbase = (quad << 1) + (ks << 3);  // 16B-chunk idx of col
            bf16x8 af[2], bfr[2];
#pragma unroll
            for (int mf = 0; mf < 2; ++mf) {
                const int row = mf * 16 + l16;
                const int sw  = row & 7;
                const float* rp = &sA[cur][row][0];
                f32x4 a = *reinterpret_cast<const f32x4*>(
                    rp + (((cbase)     ^ sw) << 2));
                f32x4 c = *reinterpret_cast<const f32x4*>(
                    rp + (((cbase + 1) ^ sw) << 2));
                bf16x8 t;
#pragma unroll
                for (int i = 0; i < 4; ++i) {
                    t[i]     = (short)f2bf(a[i]);
                    t[i + 4] = (short)f2bf(c[i]);
                }
                af[mf] = t;
            }
#pragma unroll
            for (int nf = 0; nf < 2; ++nf)
                bfr[nf] = *reinterpret_cast<const bf16x8*>(
                    bk + (size_t)nf * 16 * N_NODES + ks * 32);
#pragma unroll
            for (int mf = 0; mf < 2; ++mf)
#pragma unroll
                for (int nf = 0; nf < 2; ++nf)
                    acc[mf][nf] = __builtin_amdgcn_mfma_f32_16x16x32_bf16(
                        af[mf], bfr[nf], acc[mf][nf], 0, 0, 0);
        }

        asm volatile("s_waitcnt vmcnt(0)" ::: "memory");
        __syncthreads();
        cur ^= 1;
    }

    // C/D: row (m) = quad*4 + reg, col (o) = lane&15
#pragma unroll
    for (int mf = 0; mf < 2; ++mf)
#pragma unroll
        for (int i = 0; i < 4; ++i) {
            const int row = m0 + mf * 16 + quad * 4 + i;
#pragma unroll
            for (int nf = 0; nf < 2; ++nf) {
                const int col = wn + nf * 16 + l16;
                out[(size_t)row * OUT_DIM + col] = acc[mf][nf][i];
            }
        }
#undef STAGE2
}

extern "C" void kernel_launch(void* const* d_in, const int* in_sizes, int n_in,
                              void* d_out, int out_size, void* d_ws, size_t ws_size,
                              hipStream_t stream) {
    const float* x     = (const float*)d_in[0];
    const float* A_hat = (const float*)d_in[1];
    const float* W     = (const float*)d_in[2];
    const float* b     = (const float*)d_in[3];
    float* out         = (float*)d_out;
    unsigned short* hT = (unsigned short*)d_ws;   // 128 x 16384 bf16 = 4 MB

    gemm1_xw<<<N_NODES / 64, 256, 0, stream>>>(x, W, b, hT);
    gemm2_ah<<<N_NODES / BM2, 256, 0, stream>>>(A_hat, hT, out);
}